// Round 1
// baseline (31.143 us; speedup 1.0000x reference)
//
#include <hip/hip_runtime.h>

#define HH 96
#define WW 96
#define NPX (HH*WW)         // 9216
#define CIN 3
#define HID 16
#define OUTC 10
#define TT 8
#define BB 2
#define BETA 0.9f

#define THREADS 128
#define NWAVE 2
#define NBLK (BB*HH)        // 192

// ws float layout:
//  [0 .. NBLK*TT*NWAVE*16) : spike-count partials, float4 idx ((blk*TT+t)*NWAVE+w)*4 + cg
//  [CNT_FLOATS .. +NBLK*NWAVE) : smooth partials (per wave, summed over all t)
#define CNT_FLOATS (NBLK*TT*NWAVE*16)   // 49152 floats
#define SMOOTH_OFF CNT_FLOATS
#define SMOOTH_N (NBLK*NWAVE)           // 384
#define DENOM 2359296.0f                // T*B*N*HID

__global__ __launch_bounds__(THREADS)
void snn_main(const float* __restrict__ x,
              const float* __restrict__ wproj,
              const float* __restrict__ bproj,
              float* __restrict__ ws)
{
  // z for rows (row-1, row, row+1), [g][col][cg] as float4 (4 channels each)
  __shared__ float4 zbuf[3*WW*4];   // 18 KB
  // vertical 3-sums on the core row, [col][cg]
  __shared__ float4 cbuf[WW*4];     // 6 KB

  const int row   = blockIdx.x;   // 0..95
  const int b     = blockIdx.y;   // 0..1
  const int blk   = b*HH + row;
  const int tid   = threadIdx.x;
  const int lane  = tid & 63;
  const int wv    = tid >> 6;
  const int cg    = tid & 3;      // channel group (4 channels)
  const int pbase = tid >> 2;     // 0..31

  // per-thread weights for this channel group (hoisted out of the t-loop)
  float w0[4], w1[4], w2[4], bp[4];
#pragma unroll
  for (int j = 0; j < 4; ++j) {
    w0[j] = wproj[0*HID + cg*4 + j];
    w1[j] = wproj[1*HID + cg*4 + j];
    w2[j] = wproj[2*HID + cg*4 + j];
    bp[j] = bproj[cg*4 + j];
  }

  float4 v[3];
#pragma unroll
  for (int k = 0; k < 3; ++k) v[k] = make_float4(0.f, 0.f, 0.f, 0.f);
  float smooth_acc = 0.f;

  float4* wc = (float4*)ws;
  const float inv9 = 1.0f/9.0f;

  for (int t = 0; t < TT; ++t) {
    // ---- phase 1: z = x @ w_proj + b_proj for 3 rows (288 px x 4 cgs) ----
#pragma unroll
    for (int k = 0; k < 9; ++k) {
      int px  = pbase + 32*k;       // 0..287
      int g   = px / 96;
      int col = px - g*96;
      int rr  = row + g - 1;
      rr = (rr < 0) ? rr + HH : (rr >= HH ? rr - HH : rr);
      const float* xp = x + (size_t)((t*BB + b)*NPX + rr*WW + col)*CIN;
      float xa = xp[0], xb = xp[1], xc = xp[2];
      float4 z;
      z.x = fmaf(xc, w2[0], fmaf(xb, w1[0], fmaf(xa, w0[0], bp[0])));
      z.y = fmaf(xc, w2[1], fmaf(xb, w1[1], fmaf(xa, w0[1], bp[1])));
      z.z = fmaf(xc, w2[2], fmaf(xb, w1[2], fmaf(xa, w0[2], bp[2])));
      z.w = fmaf(xc, w2[3], fmaf(xb, w1[3], fmaf(xa, w0[3], bp[3])));
      zbuf[px*4 + cg] = z;          // linear across lanes: conflict-free
    }
    __syncthreads();

    // ---- phase 2: vertical 3-sum on core row ----
    float4 zc[3];
#pragma unroll
    for (int k = 0; k < 3; ++k) {
      int col = pbase + 32*k;       // 0..95
      float4 zu = zbuf[(0*96 + col)*4 + cg];
      float4 zm = zbuf[(1*96 + col)*4 + cg];
      float4 zd = zbuf[(2*96 + col)*4 + cg];
      zc[k] = zm;                   // keep core z for smooth term
      float4 c;
      c.x = zu.x + zm.x + zd.x;
      c.y = zu.y + zm.y + zd.y;
      c.z = zu.z + zm.z + zd.z;
      c.w = zu.w + zm.w + zd.w;
      cbuf[col*4 + cg] = c;
    }
    __syncthreads();

    // ---- phase 3: horizontal 3-sum -> agg; LIF update; reductions ----
    float4 cnt = make_float4(0.f, 0.f, 0.f, 0.f);
#pragma unroll
    for (int k = 0; k < 3; ++k) {
      int col = pbase + 32*k;
      int cl = (col == 0)    ? (WW-1) : (col-1);
      int cr = (col == WW-1) ? 0      : (col+1);
      float4 s0 = cbuf[cl*4 + cg];
      float4 s1 = cbuf[col*4 + cg];
      float4 s2 = cbuf[cr*4 + cg];
      float ax = (s0.x + s1.x + s2.x) * inv9;
      float ay = (s0.y + s1.y + s2.y) * inv9;
      float az = (s0.z + s1.z + s2.z) * inv9;
      float aw = (s0.w + s1.w + s2.w) * inv9;
      smooth_acc += fabsf(ax - zc[k].x);
      smooth_acc += fabsf(ay - zc[k].y);
      smooth_acc += fabsf(az - zc[k].z);
      smooth_acc += fabsf(aw - zc[k].w);
      // LIF: integrate, threshold, soft reset
      float vx = BETA*v[k].x + ax;
      float vy = BETA*v[k].y + ay;
      float vz = BETA*v[k].z + az;
      float vw = BETA*v[k].w + aw;
      float sx = (vx > 1.0f) ? 1.0f : 0.0f;
      float sy = (vy > 1.0f) ? 1.0f : 0.0f;
      float sz = (vz > 1.0f) ? 1.0f : 0.0f;
      float sw = (vw > 1.0f) ? 1.0f : 0.0f;
      cnt.x += sx; cnt.y += sy; cnt.z += sz; cnt.w += sw;
      v[k].x = vx - sx;
      v[k].y = vy - sy;
      v[k].z = vz - sz;
      v[k].w = vw - sw;
    }

    // wave-reduce cnt over lanes with equal (lane & 3); lanes 0..3 hold cg 0..3
#pragma unroll
    for (int off = 4; off < 64; off <<= 1) {
      cnt.x += __shfl_xor(cnt.x, off);
      cnt.y += __shfl_xor(cnt.y, off);
      cnt.z += __shfl_xor(cnt.z, off);
      cnt.w += __shfl_xor(cnt.w, off);
    }
    if (lane < 4)
      wc[((blk*TT + t)*NWAVE + wv)*4 + lane] = cnt;
    __syncthreads();   // protects cbuf (read above) vs next phase-2 write
  }

  // smooth: full 64-lane reduce, once
#pragma unroll
  for (int off = 1; off < 64; off <<= 1)
    smooth_acc += __shfl_xor(smooth_acc, off);
  if (lane == 0)
    ws[SMOOTH_OFF + blk*NWAVE + wv] = smooth_acc;
}

__global__ __launch_bounds__(256)
void snn_final(const float* __restrict__ ws,
               const float* __restrict__ whead,
               const float* __restrict__ bhead,
               float* __restrict__ out)
{
  __shared__ float cnt_s[TT][BB][HID];
  __shared__ float log_s[TT][BB][OUTC];
  const int tid = threadIdx.x;

  // 256 threads == TT*BB*HID combos: sum spike-count partials over 96 rows x 2 waves
  {
    const int t  = tid >> 5;
    const int bq = (tid >> 4) & 1;
    const int d  = tid & 15;
    const int cg = d >> 2, comp = d & 3;
    float s = 0.f;
#pragma unroll 4
    for (int r = 0; r < HH; ++r) {
      int blk = bq*HH + r;
#pragma unroll
      for (int w = 0; w < NWAVE; ++w)
        s += ws[(((blk*TT + t)*NWAVE + w)*4 + cg)*4 + comp];
    }
    cnt_s[t][bq][d] = s;
  }
  __syncthreads();

  // logits_seq[t][b][o] = (cnt/N) @ w_head + b_head
  if (tid < TT*BB*OUTC) {
    const int t  = tid / (BB*OUTC);
    const int r  = tid - t*(BB*OUTC);
    const int bq = r / OUTC;
    const int o  = r - bq*OUTC;
    float acc = bhead[o];
#pragma unroll
    for (int d = 0; d < HID; ++d)
      acc = fmaf(cnt_s[t][bq][d] / 9216.0f, whead[d*OUTC + o], acc);
    log_s[t][bq][o] = acc;
    out[20 + tid] = acc;          // logits_seq, flat (t,b,o)
  }
  __syncthreads();

  // out[b][o] = mean over t of logits
  if (tid < BB*OUTC) {
    const int bq = tid / OUTC, o = tid - bq*OUTC;
    float a = 0.f;
#pragma unroll
    for (int t = 0; t < TT; ++t) a += log_s[t][bq][o];
    out[tid] = a * (1.0f/TT);
  }
  // sr = total spikes / (T*B*N*HID)
  if (tid == 64) {
    float a = 0.f;
    for (int i = 0; i < TT*BB*HID; ++i) a += (&cnt_s[0][0][0])[i];
    out[180] = a / DENOM;
  }
  // smooth = total |agg-z| / (T*B*N*HID)
  if (tid == 65) {
    float a = 0.f;
    for (int i = 0; i < SMOOTH_N; ++i) a += ws[SMOOTH_OFF + i];
    out[181] = a / DENOM;
  }
}

extern "C" void kernel_launch(void* const* d_in, const int* in_sizes, int n_in,
                              void* d_out, int out_size, void* d_ws, size_t ws_size,
                              hipStream_t stream)
{
  const float* x     = (const float*)d_in[0];
  const float* wproj = (const float*)d_in[1];
  const float* bproj = (const float*)d_in[2];
  const float* whead = (const float*)d_in[3];
  const float* bhead = (const float*)d_in[4];
  float* out = (float*)d_out;
  float* ws  = (float*)d_ws;

  dim3 grid(HH, BB);
  snn_main<<<grid, dim3(THREADS), 0, stream>>>(x, wproj, bproj, ws);
  snn_final<<<1, dim3(256), 0, stream>>>(ws, whead, bhead, out);
}